// Round 1
// baseline (325.037 us; speedup 1.0000x reference)
//
#include <hip/hip_runtime.h>

#define BATCH 32

// Kernel 1: per-row duration scan + inverse-index scatter + totals.
// One block (256 threads) per batch row; each thread owns S/256 consecutive
// source positions.
__global__ void lr_scan_kernel(const float* __restrict__ dur,
                               const unsigned int* __restrict__ scale_raw,
                               float* __restrict__ out_tail,   // B floats (total_lengths, output 1)
                               int* __restrict__ totals,       // B ints (workspace)
                               int* __restrict__ idxmap,       // B*T ints (workspace)
                               int S, int T) {
    __shared__ int partial[256];
    const int b = blockIdx.x;
    const int tid = threadIdx.x;

    // duration_scale dtype is ambiguous (python scalar). Normal floats have
    // exponent bits set => raw >= 0x00800000; small ints don't.
    unsigned int u = scale_raw[0];
    float scale = (u < 0x00800000u) ? (float)(int)u : __uint_as_float(u);

    const int PER = S / 256;            // 4 for S=1024
    int d[8];                           // supports S up to 2048
    int lsum = 0;
    const int base = tid * PER;
    for (int k = 0; k < PER; ++k) {
        float f = dur[b * S + base + k];
        int di = (int)(f * scale + 0.5f);   // trunc of non-negative == round-half-up
        if (di < 1) di = 1;
        d[k] = di;
        lsum += di;
    }
    partial[tid] = lsum;
    __syncthreads();

    // Hillis-Steele inclusive scan over 256 per-thread sums
    for (int off = 1; off < 256; off <<= 1) {
        int t = (tid >= off) ? partial[tid - off] : 0;
        __syncthreads();
        partial[tid] += t;
        __syncthreads();
    }

    int run = partial[tid] - lsum;      // exclusive prefix = start of this thread's span
    for (int k = 0; k < PER; ++k) {
        int e = run + d[k];
        for (int j = run; j < e; ++j)
            idxmap[b * T + j] = base + k;
        run = e;
    }

    if (tid == 255) {
        int total = partial[255];
        totals[b] = total;
        out_tail[b] = (float)total;     // output dtype for the flat buffer is f32
    }
}

// Kernel 2: one thread per output float4. Coalesced 16B/lane read+write.
__global__ void lr_fill_kernel(const float4* __restrict__ x4,
                               const int* __restrict__ idxmap,
                               const int* __restrict__ totals,
                               float4* __restrict__ out4,
                               int S, int T, int D4, long long n4) {
    long long i = (long long)blockIdx.x * blockDim.x + threadIdx.x;
    if (i >= n4) return;
    const int td4 = T * D4;
    int b = (int)(i / td4);
    int r = (int)(i - (long long)b * td4);
    int t = r / D4;
    int lane = r - t * D4;
    float4 v;
    if (t < totals[b]) {
        int s = idxmap[b * T + t];
        v = x4[((long long)(b * S + s)) * D4 + lane];
    } else {
        v = make_float4(0.f, 0.f, 0.f, 0.f);
    }
    out4[i] = v;
}

extern "C" void kernel_launch(void* const* d_in, const int* in_sizes, int n_in,
                              void* d_out, int out_size, void* d_ws, size_t ws_size,
                              hipStream_t stream) {
    const float* x = (const float*)d_in[0];
    const float* dur = (const float*)d_in[1];
    const unsigned int* scale = (const unsigned int*)d_in[2];

    const int B = BATCH;
    const int D = in_sizes[0] / in_sizes[1];   // 512
    const int S = in_sizes[1] / B;             // 1024
    const int T = (out_size - B) / (B * D);    // batch-max total length

    float* out = (float*)d_out;
    float* out_tail = out + (long long)B * T * D;

    int* idxmap = (int*)d_ws;                  // B*T ints
    int* totals = idxmap + (long long)B * T;   // B ints

    lr_scan_kernel<<<B, 256, 0, stream>>>(dur, scale, out_tail, totals, idxmap, S, T);

    const int D4 = D / 4;
    const long long n4 = (long long)B * T * D4;
    const int blocks = (int)((n4 + 255) / 256);
    lr_fill_kernel<<<blocks, 256, 0, stream>>>((const float4*)x, idxmap, totals,
                                               (float4*)out, S, T, D4, n4);
}

// Round 4
// 307.171 us; speedup vs baseline: 1.0582x; 1.0582x over previous
//
#include <hip/hip_runtime.h>

#define BATCH 32

typedef float f32x4 __attribute__((ext_vector_type(4)));

// Kernel 1: per-row duration scan + inverse-index scatter + totals.
// One block (256 threads) per batch row; each thread owns S/256 consecutive
// source positions.
__global__ void lr_scan_kernel(const float* __restrict__ dur,
                               const unsigned int* __restrict__ scale_raw,
                               float* __restrict__ out_tail,   // B floats (total_lengths, output 1)
                               int* __restrict__ totals,       // B ints (workspace)
                               int* __restrict__ idxmap,       // B*T ints (workspace)
                               int S, int T) {
    __shared__ int partial[256];
    const int b = blockIdx.x;
    const int tid = threadIdx.x;

    // duration_scale dtype is ambiguous (python scalar). Normal floats have
    // exponent bits set => raw >= 0x00800000; small ints don't.
    unsigned int u = scale_raw[0];
    float scale = (u < 0x00800000u) ? (float)(int)u : __uint_as_float(u);

    const int PER = S / 256;            // 4 for S=1024
    int d[8];                           // supports S up to 2048
    int lsum = 0;
    const int base = tid * PER;
    for (int k = 0; k < PER; ++k) {
        float f = dur[b * S + base + k];
        int di = (int)(f * scale + 0.5f);   // trunc of non-negative == round-half-up
        if (di < 1) di = 1;
        d[k] = di;
        lsum += di;
    }
    partial[tid] = lsum;
    __syncthreads();

    // Hillis-Steele inclusive scan over 256 per-thread sums
    for (int off = 1; off < 256; off <<= 1) {
        int t = (tid >= off) ? partial[tid - off] : 0;
        __syncthreads();
        partial[tid] += t;
        __syncthreads();
    }

    int run = partial[tid] - lsum;      // exclusive prefix = start of this thread's span
    for (int k = 0; k < PER; ++k) {
        int e = run + d[k];
        for (int j = run; j < e; ++j)
            idxmap[b * T + j] = base + k;
        run = e;
    }

    if (tid == 255) {
        int total = partial[255];
        totals[b] = total;
        out_tail[b] = (float)total;     // output dtype for the flat buffer is f32
    }
}

// Kernel 2: 2D grid — blockIdx.y = batch, each 256-thread block covers
// 256>>d4shift output frames. All index math is shifts/masks (no division).
// Nontemporal stores keep x resident in L2/L3 for the gather re-reads.
__global__ __launch_bounds__(256) void lr_fill_kernel(
        const f32x4* __restrict__ x4,
        const int* __restrict__ idxmap,
        const int* __restrict__ totals,
        f32x4* __restrict__ out4,
        int S, int T, int d4shift) {
    const int b = blockIdx.y;
    const int D4m1 = (1 << d4shift) - 1;
    const int lane = threadIdx.x & D4m1;
    const int fpb = 256 >> d4shift;                       // frames per block
    const int t = blockIdx.x * fpb + (threadIdx.x >> d4shift);
    if (t >= T) return;

    f32x4 v = (f32x4)(0.f, 0.f, 0.f, 0.f);
    if (t < totals[b]) {
        const int s = idxmap[b * T + t];                  // broadcast within half-wave
        v = x4[(((long long)(b * S + s)) << d4shift) + lane];
    }
    __builtin_nontemporal_store(v, &out4[(((long long)(b * T + t)) << d4shift) + lane]);
}

extern "C" void kernel_launch(void* const* d_in, const int* in_sizes, int n_in,
                              void* d_out, int out_size, void* d_ws, size_t ws_size,
                              hipStream_t stream) {
    const float* x = (const float*)d_in[0];
    const float* dur = (const float*)d_in[1];
    const unsigned int* scale = (const unsigned int*)d_in[2];

    const int B = BATCH;
    const int D = in_sizes[0] / in_sizes[1];   // 512
    const int S = in_sizes[1] / B;             // 1024
    const int T = (out_size - B) / (B * D);    // batch-max total length

    float* out = (float*)d_out;
    float* out_tail = out + (long long)B * T * D;

    int* idxmap = (int*)d_ws;                  // B*T ints
    int* totals = idxmap + (long long)B * T;   // B ints

    lr_scan_kernel<<<B, 256, 0, stream>>>(dur, scale, out_tail, totals, idxmap, S, T);

    const int D4 = D / 4;                      // 128, power of two
    int d4shift = 0;
    while ((1 << d4shift) < D4) ++d4shift;     // 7
    const int fpb = 256 >> d4shift;            // frames per 256-thread block
    dim3 grid((T + fpb - 1) / fpb, B);
    lr_fill_kernel<<<grid, 256, 0, stream>>>((const f32x4*)x, idxmap, totals,
                                             (f32x4*)out, S, T, d4shift);
}